// Round 2
// baseline (509.025 us; speedup 1.0000x reference)
//
#include <hip/hip_runtime.h>
#include <hip/hip_bf16.h>

// Problem: B=128, T=256, D=1024.  TOK = B*T = 32768.
// keys = x@Wk.T+bk ; queries = x@Wq.T+bq ; values = x@Wv.T+bv
// S = tril(Q K^T / 32) ; P = softmax(S) ; out = P V   (fp32 out)

typedef __attribute__((ext_vector_type(4))) float f32x4;
typedef __attribute__((ext_vector_type(8))) short s16x8;
typedef unsigned short u16;

__device__ inline u16 f2bf(float f) {
    union { __hip_bfloat16 h; u16 u; } c;
    c.h = __float2bfloat16(f);
    return c.u;
}

// async global->LDS DMA, 16B per lane, dest = wave-uniform base + lane*16
__device__ __forceinline__ void stage16(const void* g, void* l) {
    __builtin_amdgcn_global_load_lds((const __attribute__((address_space(1))) void*)g,
                                     (__attribute__((address_space(3))) void*)l, 16, 0, 0);
}

// ---------------- fp32 -> bf16 convert ----------------
__global__ __launch_bounds__(256) void cvt_f32_bf16(const float* __restrict__ in,
                                                    u16* __restrict__ out, int n4) {
    int stride = gridDim.x * blockDim.x;
    for (int i = blockIdx.x * blockDim.x + threadIdx.x; i < n4; i += stride) {
        float4 v = reinterpret_cast<const float4*>(in)[i];
        ushort4 o = make_ushort4(f2bf(v.x), f2bf(v.y), f2bf(v.z), f2bf(v.w));
        reinterpret_cast<ushort4*>(out)[i] = o;
    }
}

// ---------------- shared 128x128-tile BF16 MFMA mainloop ----------------
// NT layout: A rows [128][lda] contiguous along k; B^T rows [128][ldb] contiguous along k.
// 4 waves (2x2), each computes a 64x64 sub-tile as 4x4 fragments of 16x16x32.
// Staging via global_load_lds width=16: per wave, one DMA per 8-row group.
// LDS layout [128][64] bf16 linear; wave w / iter it covers rows it*32 + w*8 .. +8,
// i.e. LDS byte base it*4096 + w*1024, lane l -> +l*16 (row base + (l>>3)*128 + (l&7)*16).
__device__ inline void gemm_mainloop(const u16* __restrict__ Ap, const u16* __restrict__ Bp,
                                     int lda, int ldb, int kLen,
                                     u16* As, u16* Bs, f32x4 (&acc)[4][4]) {
    const int tid  = threadIdx.x;
    const int lane = tid & 63;
    const int w    = tid >> 6;          // wave 0..3
    const int wr   = (tid >> 7) & 1;
    const int wc   = (tid >> 6) & 1;
    const int lr   = lane >> 3;         // 0..7 row within 8-row group
    const int lc   = (lane & 7) << 3;   // 0..56 col (8 bf16 = 16B per lane)

    for (int k0 = 0; k0 < kLen; k0 += 64) {
#pragma unroll
        for (int it = 0; it < 4; ++it) {
            const int r = it * 32 + w * 8 + lr;
            stage16(&Ap[(size_t)r * lda + k0 + lc], &As[it * 2048 + w * 512]);
            stage16(&Bp[(size_t)r * ldb + k0 + lc], &Bs[it * 2048 + w * 512]);
        }
        __syncthreads();   // compiler emits vmcnt(0) drain before s_barrier
#pragma unroll
        for (int kk = 0; kk < 64; kk += 32) {
            const int kcol = kk + (lane >> 4) * 8;
            s16x8 a[4], bfr[4];
#pragma unroll
            for (int m = 0; m < 4; ++m)
                a[m] = *reinterpret_cast<const s16x8*>(&As[(wr * 64 + m * 16 + (lane & 15)) * 64 + kcol]);
#pragma unroll
            for (int n = 0; n < 4; ++n)
                bfr[n] = *reinterpret_cast<const s16x8*>(&Bs[(wc * 64 + n * 16 + (lane & 15)) * 64 + kcol]);
#pragma unroll
            for (int m = 0; m < 4; ++m)
#pragma unroll
                for (int n = 0; n < 4; ++n)
                    acc[m][n] = __builtin_amdgcn_mfma_f32_16x16x32_bf16(a[m], bfr[n], acc[m][n], 0, 0, 0);
        }
        __syncthreads();
    }
}

// ---------------- QKV projection: out = x @ W.T + b ----------------
// grid = 256 m-tiles * 24 n-tiles (3 mats x 8 col-tiles). V is written transposed:
// Vt[b][d][t] so the PV GEMM is also NT.
__global__ __launch_bounds__(256) void qkv_gemm(const u16* __restrict__ X, const u16* __restrict__ W3,
                                                const float* __restrict__ biasK,
                                                const float* __restrict__ biasQ,
                                                const float* __restrict__ biasV,
                                                u16* __restrict__ Kb, u16* __restrict__ Qb,
                                                u16* __restrict__ Vt) {
    __shared__ u16 As[128 * 64];
    __shared__ u16 Bs[128 * 64];
    const int bid  = blockIdx.x;
    const int nt   = bid % 24;
    const int mt   = bid / 24;
    const int nmat = nt >> 3;
    const int ncol = nt & 7;
    const u16* Ap = X + (size_t)mt * 128 * 1024;
    const u16* Bp = W3 + (size_t)nmat * 1024 * 1024 + (size_t)ncol * 128 * 1024;

    f32x4 acc[4][4] = {};
    gemm_mainloop(Ap, Bp, 1024, 1024, 1024, As, Bs, acc);

    const int tid  = threadIdx.x;
    const int lane = tid & 63;
    const int wr   = (tid >> 7) & 1;
    const int wc   = (tid >> 6) & 1;
    const float* bias = (nmat == 0) ? biasK : (nmat == 1) ? biasQ : biasV;
    u16* outKQ = (nmat == 0) ? Kb : Qb;
    const int r0 = (lane >> 4) << 2;
    const int c0 = lane & 15;
#pragma unroll
    for (int m = 0; m < 4; ++m) {
#pragma unroll
        for (int n = 0; n < 4; ++n) {
            const int colg = ncol * 128 + wc * 64 + n * 16 + c0;
            const float bvv = bias[colg];
#pragma unroll
            for (int j = 0; j < 4; ++j) {
                const int rowg = mt * 128 + wr * 64 + m * 16 + r0 + j;
                const u16 hb = f2bf(acc[m][n][j] + bvv);
                if (nmat == 2) {
                    const int b = rowg >> 8, t = rowg & 255;
                    Vt[(size_t)b * 262144 + (size_t)colg * 256 + t] = hb;
                } else {
                    outKQ[(size_t)rowg * 1024 + colg] = hb;
                }
            }
        }
    }
}

// ---------------- scores: S = tril(Q K^T * 1/32) per batch ----------------
// grid = 128 batches * 3 lower-triangle 128x128 tiles.
__global__ __launch_bounds__(256) void scores_gemm(const u16* __restrict__ Qb,
                                                   const u16* __restrict__ Kb,
                                                   float* __restrict__ S) {
    __shared__ u16 As[128 * 64];
    __shared__ u16 Bs[128 * 64];
    const int bid = blockIdx.x;
    const int b   = bid / 3;
    const int rem = bid % 3;
    const int ti  = (rem == 0) ? 0 : 1;
    const int si  = (rem == 2) ? 1 : 0;
    const u16* Ap = Qb + ((size_t)b * 256 + (size_t)ti * 128) * 1024;
    const u16* Bp = Kb + ((size_t)b * 256 + (size_t)si * 128) * 1024;

    f32x4 acc[4][4] = {};
    gemm_mainloop(Ap, Bp, 1024, 1024, 1024, As, Bs, acc);

    const int tid  = threadIdx.x;
    const int lane = tid & 63;
    const int wr   = (tid >> 7) & 1;
    const int wc   = (tid >> 6) & 1;
    const int r0 = (lane >> 4) << 2;
    const int c0 = lane & 15;
    const float scale = 0.03125f;
#pragma unroll
    for (int m = 0; m < 4; ++m) {
#pragma unroll
        for (int n = 0; n < 4; ++n) {
            const int s = si * 128 + wc * 64 + n * 16 + c0;
#pragma unroll
            for (int j = 0; j < 4; ++j) {
                const int t = ti * 128 + wr * 64 + m * 16 + r0 + j;
                float v = acc[m][n][j] * scale;
                if (s > t) v = -__builtin_inff();
                S[(size_t)b * 65536 + (size_t)t * 256 + s] = v;
            }
        }
    }
}

// ---------------- row softmax -> P (bf16), zeros above diagonal ----------------
// one wave per row; 4 rows per block.
__global__ __launch_bounds__(256) void softmax_p(const float* __restrict__ S, u16* __restrict__ P) {
    const int row  = blockIdx.x * 4 + (threadIdx.x >> 6);  // 0..32767
    const int lane = threadIdx.x & 63;
    const int b = row >> 8, t = row & 255;
    const float* Sp = S + (size_t)b * 65536 + (size_t)t * 256;
    const int s0 = lane * 4;
    float4 v = reinterpret_cast<const float4*>(Sp)[lane];
    const float NEG = -__builtin_inff();
    float x0 = (s0 + 0 <= t) ? v.x : NEG;
    float x1 = (s0 + 1 <= t) ? v.y : NEG;
    float x2 = (s0 + 2 <= t) ? v.z : NEG;
    float x3 = (s0 + 3 <= t) ? v.w : NEG;
    float mx = fmaxf(fmaxf(x0, x1), fmaxf(x2, x3));
#pragma unroll
    for (int off = 1; off < 64; off <<= 1) mx = fmaxf(mx, __shfl_xor(mx, off, 64));
    float e0 = (s0 + 0 <= t) ? __expf(x0 - mx) : 0.f;
    float e1 = (s0 + 1 <= t) ? __expf(x1 - mx) : 0.f;
    float e2 = (s0 + 2 <= t) ? __expf(x2 - mx) : 0.f;
    float e3 = (s0 + 3 <= t) ? __expf(x3 - mx) : 0.f;
    float sum = e0 + e1 + e2 + e3;
#pragma unroll
    for (int off = 1; off < 64; off <<= 1) sum += __shfl_xor(sum, off, 64);
    const float inv = 1.0f / sum;
    ushort4 o = make_ushort4(f2bf(e0 * inv), f2bf(e1 * inv), f2bf(e2 * inv), f2bf(e3 * inv));
    reinterpret_cast<ushort4*>(P + (size_t)row * 256)[lane] = o;
}

// ---------------- PV: out = P @ V  (Vt is [b][d][t] so NT) ----------------
// grid = 128 batches * 2 m-tiles * 8 n-tiles; K clipped by causality.
__global__ __launch_bounds__(256) void pv_gemm(const u16* __restrict__ P, const u16* __restrict__ Vt,
                                               float* __restrict__ O) {
    __shared__ u16 As[128 * 64];
    __shared__ u16 Bs[128 * 64];
    const int bid = blockIdx.x;
    const int b   = bid >> 4;
    const int r   = bid & 15;
    const int mt  = r >> 3;
    const int ntl = r & 7;
    const u16* Ap = P + (size_t)b * 65536 + (size_t)mt * 128 * 256;     // lda 256
    const u16* Bp = Vt + (size_t)b * 262144 + (size_t)ntl * 128 * 256;  // ldb 256
    const int kmax = (mt + 1) * 128;  // rows <128 never need s>=128 (P there is 0)

    f32x4 acc[4][4] = {};
    gemm_mainloop(Ap, Bp, 256, 256, kmax, As, Bs, acc);

    const int tid  = threadIdx.x;
    const int lane = tid & 63;
    const int wr   = (tid >> 7) & 1;
    const int wc   = (tid >> 6) & 1;
    const int r0 = (lane >> 4) << 2;
    const int c0 = lane & 15;
#pragma unroll
    for (int m = 0; m < 4; ++m) {
#pragma unroll
        for (int n = 0; n < 4; ++n) {
            const int d = ntl * 128 + wc * 64 + n * 16 + c0;
#pragma unroll
            for (int j = 0; j < 4; ++j) {
                const int t = mt * 128 + wr * 64 + m * 16 + r0 + j;
                O[((size_t)b * 256 + t) * 1024 + d] = acc[m][n][j];
            }
        }
    }
}

// ---------------- launcher ----------------
extern "C" void kernel_launch(void* const* d_in, const int* in_sizes, int n_in,
                              void* d_out, int out_size, void* d_ws, size_t ws_size,
                              hipStream_t stream) {
    (void)in_sizes; (void)n_in; (void)out_size; (void)ws_size;
    const float* x  = (const float*)d_in[0];
    const float* Wk = (const float*)d_in[1];
    const float* bk = (const float*)d_in[2];
    const float* Wq = (const float*)d_in[3];
    const float* bq = (const float*)d_in[4];
    const float* Wv = (const float*)d_in[5];
    const float* bv = (const float*)d_in[6];
    float* out = (float*)d_out;
    char* ws = (char*)d_ws;

    // ws layout (bytes):
    //   [0,            67108864)  xb   bf16 x  [32768][1024]   (reused below)
    //   [67108864,     73400320)  Wb   bf16 Wk|Wq|Wv  [3][1024][1024]
    //   [73400320,    140509184)  Kb   bf16 keys    [32768][1024]
    //   [140509184,   207618048)  Qb   bf16 queries [32768][1024]
    //   [207618048,   274726912)  Vt   bf16 values^T [128][1024][256]
    //   overlay after qkv_gemm:  S f32 [128][256][256] at 0 ; P bf16 at 33554432
    u16*   xb = (u16*)(ws + 0);
    u16*   Wb = (u16*)(ws + 67108864);
    u16*   Kb = (u16*)(ws + 73400320);
    u16*   Qb = (u16*)(ws + 140509184);
    u16*   Vt = (u16*)(ws + 207618048);
    float* S  = (float*)(ws + 0);
    u16*   P  = (u16*)(ws + 33554432);

    cvt_f32_bf16<<<2048, 256, 0, stream>>>(x, xb, 33554432 / 4);
    cvt_f32_bf16<<<512, 256, 0, stream>>>(Wk, Wb, 1048576 / 4);
    cvt_f32_bf16<<<512, 256, 0, stream>>>(Wq, Wb + 1048576, 1048576 / 4);
    cvt_f32_bf16<<<512, 256, 0, stream>>>(Wv, Wb + 2097152, 1048576 / 4);
    qkv_gemm<<<6144, 256, 0, stream>>>(xb, Wb, bk, bq, bv, Kb, Qb, Vt);
    scores_gemm<<<384, 256, 0, stream>>>(Qb, Kb, S);
    softmax_p<<<8192, 256, 0, stream>>>(S, P);
    pv_gemm<<<2048, 256, 0, stream>>>(P, Vt, out);
}

// Round 3
// 424.081 us; speedup vs baseline: 1.2003x; 1.2003x over previous
//
#include <hip/hip_runtime.h>
#include <hip/hip_bf16.h>

// Problem: B=128, T=256, D=1024.  TOK = B*T = 32768.
// keys = x@Wk.T+bk ; queries = x@Wq.T+bq ; values = x@Wv.T+bv
// S = tril(Q K^T / 32) ; P = softmax(S) ; out = P V   (fp32 out)

typedef __attribute__((ext_vector_type(4))) float f32x4;
typedef __attribute__((ext_vector_type(8))) short s16x8;
typedef unsigned short u16;

__device__ inline u16 f2bf(float f) {
    union { __hip_bfloat16 h; u16 u; } c;
    c.h = __float2bfloat16(f);
    return c.u;
}

// async global->LDS DMA, 16B/lane, dest = wave-uniform base + lane*16
__device__ __forceinline__ void stage16(const void* g, void* l) {
    __builtin_amdgcn_global_load_lds((const __attribute__((address_space(1))) void*)g,
                                     (__attribute__((address_space(3))) void*)l, 16, 0, 0);
}

#define FENCE() asm volatile("" ::: "memory")
#define BAR() do { FENCE(); __builtin_amdgcn_s_barrier(); \
                   __builtin_amdgcn_sched_barrier(0); FENCE(); } while (0)
#define MFMA(a_, b_, c_) (c_) = __builtin_amdgcn_mfma_f32_16x16x32_bf16((a_), (b_), (c_), 0, 0, 0)

// ---------------- fp32 -> bf16 convert ----------------
__global__ __launch_bounds__(256) void cvt_f32_bf16(const float* __restrict__ in,
                                                    u16* __restrict__ out, int n4) {
    int stride = gridDim.x * blockDim.x;
    for (int i = blockIdx.x * blockDim.x + threadIdx.x; i < n4; i += stride) {
        float4 v = reinterpret_cast<const float4*>(in)[i];
        ushort4 o = make_ushort4(f2bf(v.x), f2bf(v.y), f2bf(v.z), f2bf(v.w));
        reinterpret_cast<ushort4*>(out)[i] = o;
    }
}

// ============ 256x256-tile 8-phase QKV GEMM (T1+T2+T3+T4+T5) ============
// C[32768,3072] = X @ W3^T + bias.  BM=BN=256, BK=64, 512 thr = 8 waves (2Mx4N),
// per-wave 128x64.  LDS 128 KiB: buf[2] x { A0,A1,B0,B1 } halves of 128x64 bf16.
// K-tile t lives in buf[t&1].  Per K-tile, 4 phases:
//   P1: ds-read A(mh0) 8 + B(nh0) 4; stage K(t+1).A1; bar; mfma Q(mh0,nh0); bar
//   P2: ds-read B(nh1) 4;            stage K(t+1).B0; bar; mfma Q(mh0,nh1); bar
//   P3: ds-read A(mh1) 8;            stage K(t+1).B1; bar; mfma Q(mh1,nh0); bar
//   P4:                              stage K(t+2).A0; vmcnt(2); bar; mfma Q(mh1,nh1); bar
// WAR: each region's overwrite-stage issues >=1 barrier after its last read
// (A0 read P1/P3, staged next at P4; A1 read P1/P3, staged (t+1).P1; B0 read
// P1/P2, staged (t+1).P2; B1 read P1/P2, staged (t+1).P3).  RAW: vmcnt(2) at
// t.P4 retires exactly K(t+1)'s 8 loads, leaving K(t+2).A0 in flight.
// LDS swizzle: phys 16B-slot = logical_slot ^ (row&7); DMA dest linear, global
// source pre-swizzled with the same involution; reads apply it too.
__global__ __launch_bounds__(512, 2) void qkv256(const u16* __restrict__ X, const u16* __restrict__ W3,
                                                 const float* __restrict__ biasK,
                                                 const float* __restrict__ biasQ,
                                                 const float* __restrict__ biasV,
                                                 u16* __restrict__ Kb, u16* __restrict__ Qb,
                                                 u16* __restrict__ Vt) {
    extern __shared__ char lds[];  // 131072 B: buf b at b*65536; A0 +0, A1 +16384, B0 +32768, B1 +49152

    const int bid = blockIdx.x;
    const int swz = (bid & 7) * 192 + (bid >> 3);  // 1536 % 8 == 0: bijective XCD swizzle
    const int mt = swz / 12, nt2 = swz % 12;
    const int nmat = nt2 >> 2, ncol = nt2 & 3;
    const u16* Asrc = X + (size_t)mt * 256 * 1024;
    const u16* Bsrc = W3 + (size_t)nmat * 1048576 + (size_t)ncol * 256 * 1024;

    const int tid  = threadIdx.x;
    const int lane = tid & 63, w = tid >> 6;
    const int wr = w >> 2, wc = w & 3;
    const int l15 = lane & 15, l16 = lane >> 4;
    const int sw0 = ((0 + l16) ^ (l15 & 7)) << 4;  // kk=0: slots 0..3
    const int sw1 = ((4 + l16) ^ (l15 & 7)) << 4;  // kk=1: slots 4..7
    const int lr = lane >> 3, ls = lane & 7;
    const int stg_col = (ls ^ lr) << 3;            // pre-swizzled source slot (elements)

    // stage one 128x64 half-tile: srcHalf = row0 of the 128-row panel (ld=1024)
    auto STG = [&](const u16* srcHalf, int colbase, char* dstHalf) {
        const u16* s0 = srcHalf + (size_t)(w * 16 + lr) * 1024 + colbase + stg_col;
        stage16(s0,            dstHalf + w * 2048);
        stage16(s0 + 8 * 1024, dstHalf + w * 2048 + 1024);
    };

    f32x4 acc[8][4] = {};
    s16x8 af[4][2], bf[4][2];

    // ---- prologue: K0 {A0,A1,B0,B1} -> buf0, K1.A0 -> buf1 ----
    STG(Asrc,              0, lds + 0);
    STG(Asrc + 128 * 1024, 0, lds + 16384);
    STG(Bsrc,              0, lds + 32768);
    STG(Bsrc + 128 * 1024, 0, lds + 49152);
    STG(Asrc,             64, lds + 65536 + 0);
    asm volatile("s_waitcnt vmcnt(2)" ::: "memory");
    BAR();

    for (int t = 0; t < 16; ++t) {
        char* bufc = lds + (t & 1) * 65536;
        char* bufn = lds + ((t + 1) & 1) * 65536;
        const char* Ah = bufc + wr * 16384;
        const char* Bh = bufc + 32768 + (wc >> 1) * 16384;
        const int brow = (wc & 1) * 64;
        const int nk = (t + 1) * 64;

        // ---- P1 ----
#pragma unroll
        for (int fm = 0; fm < 4; ++fm) {
            const int r = fm * 16 + l15;
            af[fm][0] = *(const s16x8*)(Ah + r * 128 + sw0);
            af[fm][1] = *(const s16x8*)(Ah + r * 128 + sw1);
        }
#pragma unroll
        for (int fn = 0; fn < 2; ++fn) {
            const int r = brow + fn * 16 + l15;
            bf[fn][0] = *(const s16x8*)(Bh + r * 128 + sw0);
            bf[fn][1] = *(const s16x8*)(Bh + r * 128 + sw1);
        }
        if (t < 15) STG(Asrc + 128 * 1024, nk, bufn + 16384);  // K(t+1).A1
        BAR();
        __builtin_amdgcn_s_setprio(1);
#pragma unroll
        for (int fm = 0; fm < 4; ++fm)
#pragma unroll
            for (int fn = 0; fn < 2; ++fn) {
                MFMA(af[fm][0], bf[fn][0], acc[fm][fn]);
                MFMA(af[fm][1], bf[fn][1], acc[fm][fn]);
            }
        __builtin_amdgcn_s_setprio(0);
        BAR();

        // ---- P2 ----
#pragma unroll
        for (int fn = 2; fn < 4; ++fn) {
            const int r = brow + fn * 16 + l15;
            bf[fn][0] = *(const s16x8*)(Bh + r * 128 + sw0);
            bf[fn][1] = *(const s16x8*)(Bh + r * 128 + sw1);
        }
        if (t < 15) STG(Bsrc, nk, bufn + 32768);  // K(t+1).B0
        BAR();
        __builtin_amdgcn_s_setprio(1);
#pragma unroll
        for (int fm = 0; fm < 4; ++fm)
#pragma unroll
            for (int fn = 2; fn < 4; ++fn) {
                MFMA(af[fm][0], bf[fn][0], acc[fm][fn]);
                MFMA(af[fm][1], bf[fn][1], acc[fm][fn]);
            }
        __builtin_amdgcn_s_setprio(0);
        BAR();

        // ---- P3 ----
#pragma unroll
        for (int fm = 0; fm < 4; ++fm) {
            const int r = 64 + fm * 16 + l15;
            af[fm][0] = *(const s16x8*)(Ah + r * 128 + sw0);
            af[fm][1] = *(const s16x8*)(Ah + r * 128 + sw1);
        }
        if (t < 15) STG(Bsrc + 128 * 1024, nk, bufn + 49152);  // K(t+1).B1
        BAR();
        __builtin_amdgcn_s_setprio(1);
#pragma unroll
        for (int fm = 0; fm < 4; ++fm)
#pragma unroll
            for (int fn = 0; fn < 2; ++fn) {
                MFMA(af[fm][0], bf[fn][0], acc[fm + 4][fn]);
                MFMA(af[fm][1], bf[fn][1], acc[fm + 4][fn]);
            }
        __builtin_amdgcn_s_setprio(0);
        BAR();

        // ---- P4 ----
        if (t < 14) {
            STG(Asrc, (t + 2) * 64, bufc + 0);  // K(t+2).A0 -> buf[t&1]
            asm volatile("s_waitcnt vmcnt(2)" ::: "memory");
        } else if (t == 14) {
            asm volatile("s_waitcnt vmcnt(0)" ::: "memory");
        }
        BAR();
        __builtin_amdgcn_s_setprio(1);
#pragma unroll
        for (int fm = 0; fm < 4; ++fm)
#pragma unroll
            for (int fn = 2; fn < 4; ++fn) {
                MFMA(af[fm][0], bf[fn][0], acc[fm + 4][fn]);
                MFMA(af[fm][1], bf[fn][1], acc[fm + 4][fn]);
            }
        __builtin_amdgcn_s_setprio(0);
        BAR();
    }

    // ---- epilogue: bias + convert + store ----
    const float* bias = (nmat == 0) ? biasK : (nmat == 1) ? biasQ : biasV;
    u16* outKQ = (nmat == 0) ? Kb : Qb;
    const int colbase = ncol * 256 + wc * 64;
#pragma unroll
    for (int FM = 0; FM < 8; ++FM) {
#pragma unroll
        for (int fn = 0; fn < 4; ++fn) {
            const int col = colbase + fn * 16 + l15;
            const float bvv = bias[col];
            const int rbase = mt * 256 + wr * 128 + FM * 16 + (l16 << 2);
#pragma unroll
            for (int j = 0; j < 4; ++j) {
                const int row = rbase + j;
                const u16 hb = f2bf(acc[FM][fn][j] + bvv);
                if (nmat == 2) {
                    const int b = row >> 8, tt = row & 255;
                    Vt[(size_t)b * 262144 + (size_t)col * 256 + tt] = hb;
                } else {
                    outKQ[(size_t)row * 1024 + col] = hb;
                }
            }
        }
    }
}

// ---------------- R1 reg-staged 128x128 mainloop (scores / pv) ----------------
__device__ inline void gemm_mainloop(const u16* __restrict__ Ap, const u16* __restrict__ Bp,
                                     int lda, int ldb, int kLen,
                                     u16* As, u16* Bs, f32x4 (&acc)[4][4]) {
    const int tid  = threadIdx.x;
    const int lane = tid & 63;
    const int wr   = (tid >> 7) & 1;
    const int wc   = (tid >> 6) & 1;
    const int sr   = tid >> 3;
    const int sc   = (tid & 7) << 3;

    for (int k0 = 0; k0 < kLen; k0 += 64) {
#pragma unroll
        for (int it = 0; it < 4; ++it) {
            int r = it * 32 + sr;
            *reinterpret_cast<s16x8*>(&As[r * 64 + sc]) =
                *reinterpret_cast<const s16x8*>(&Ap[(size_t)r * lda + k0 + sc]);
            *reinterpret_cast<s16x8*>(&Bs[r * 64 + sc]) =
                *reinterpret_cast<const s16x8*>(&Bp[(size_t)r * ldb + k0 + sc]);
        }
        __syncthreads();
#pragma unroll
        for (int kk = 0; kk < 64; kk += 32) {
            const int kcol = kk + (lane >> 4) * 8;
            s16x8 a[4], bfr[4];
#pragma unroll
            for (int m = 0; m < 4; ++m)
                a[m] = *reinterpret_cast<const s16x8*>(&As[(wr * 64 + m * 16 + (lane & 15)) * 64 + kcol]);
#pragma unroll
            for (int n = 0; n < 4; ++n)
                bfr[n] = *reinterpret_cast<const s16x8*>(&Bs[(wc * 64 + n * 16 + (lane & 15)) * 64 + kcol]);
#pragma unroll
            for (int m = 0; m < 4; ++m)
#pragma unroll
                for (int n = 0; n < 4; ++n)
                    acc[m][n] = __builtin_amdgcn_mfma_f32_16x16x32_bf16(a[m], bfr[n], acc[m][n], 0, 0, 0);
        }
        __syncthreads();
    }
}

// ---------------- scores: S = tril(Q K^T * 1/32) per batch ----------------
__global__ __launch_bounds__(256) void scores_gemm(const u16* __restrict__ Qb,
                                                   const u16* __restrict__ Kb,
                                                   float* __restrict__ S) {
    __shared__ u16 As[128 * 64];
    __shared__ u16 Bs[128 * 64];
    const int bid = blockIdx.x;
    const int b   = bid / 3;
    const int rem = bid % 3;
    const int ti  = (rem == 0) ? 0 : 1;
    const int si  = (rem == 2) ? 1 : 0;
    const u16* Ap = Qb + ((size_t)b * 256 + (size_t)ti * 128) * 1024;
    const u16* Bp = Kb + ((size_t)b * 256 + (size_t)si * 128) * 1024;

    f32x4 acc[4][4] = {};
    gemm_mainloop(Ap, Bp, 1024, 1024, 1024, As, Bs, acc);

    const int tid  = threadIdx.x;
    const int lane = tid & 63;
    const int wr   = (tid >> 7) & 1;
    const int wc   = (tid >> 6) & 1;
    const int r0 = (lane >> 4) << 2;
    const int c0 = lane & 15;
    const float scale = 0.03125f;
#pragma unroll
    for (int m = 0; m < 4; ++m) {
#pragma unroll
        for (int n = 0; n < 4; ++n) {
            const int s = si * 128 + wc * 64 + n * 16 + c0;
#pragma unroll
            for (int j = 0; j < 4; ++j) {
                const int t = ti * 128 + wr * 64 + m * 16 + r0 + j;
                float v = acc[m][n][j] * scale;
                if (s > t) v = -__builtin_inff();
                S[(size_t)b * 65536 + (size_t)t * 256 + s] = v;
            }
        }
    }
}

// ---------------- row softmax -> P (bf16), zeros above diagonal ----------------
__global__ __launch_bounds__(256) void softmax_p(const float* __restrict__ S, u16* __restrict__ P) {
    const int row  = blockIdx.x * 4 + (threadIdx.x >> 6);
    const int lane = threadIdx.x & 63;
    const int b = row >> 8, t = row & 255;
    const float* Sp = S + (size_t)b * 65536 + (size_t)t * 256;
    const int s0 = lane * 4;
    float4 v = reinterpret_cast<const float4*>(Sp)[lane];
    const float NEG = -__builtin_inff();
    float x0 = (s0 + 0 <= t) ? v.x : NEG;
    float x1 = (s0 + 1 <= t) ? v.y : NEG;
    float x2 = (s0 + 2 <= t) ? v.z : NEG;
    float x3 = (s0 + 3 <= t) ? v.w : NEG;
    float mx = fmaxf(fmaxf(x0, x1), fmaxf(x2, x3));
#pragma unroll
    for (int off = 1; off < 64; off <<= 1) mx = fmaxf(mx, __shfl_xor(mx, off, 64));
    float e0 = (s0 + 0 <= t) ? __expf(x0 - mx) : 0.f;
    float e1 = (s0 + 1 <= t) ? __expf(x1 - mx) : 0.f;
    float e2 = (s0 + 2 <= t) ? __expf(x2 - mx) : 0.f;
    float e3 = (s0 + 3 <= t) ? __expf(x3 - mx) : 0.f;
    float sum = e0 + e1 + e2 + e3;
#pragma unroll
    for (int off = 1; off < 64; off <<= 1) sum += __shfl_xor(sum, off, 64);
    const float inv = 1.0f / sum;
    ushort4 o = make_ushort4(f2bf(e0 * inv), f2bf(e1 * inv), f2bf(e2 * inv), f2bf(e3 * inv));
    reinterpret_cast<ushort4*>(P + (size_t)row * 256)[lane] = o;
}

// ---------------- PV: out = P @ V  (Vt is [b][d][t] so NT) ----------------
__global__ __launch_bounds__(256) void pv_gemm(const u16* __restrict__ P, const u16* __restrict__ Vt,
                                               float* __restrict__ O) {
    __shared__ u16 As[128 * 64];
    __shared__ u16 Bs[128 * 64];
    const int bid = blockIdx.x;
    const int b   = bid >> 4;
    const int r   = bid & 15;
    const int mt  = r >> 3;
    const int ntl = r & 7;
    const u16* Ap = P + (size_t)b * 65536 + (size_t)mt * 128 * 256;
    const u16* Bp = Vt + (size_t)b * 262144 + (size_t)ntl * 128 * 256;
    const int kmax = (mt + 1) * 128;

    f32x4 acc[4][4] = {};
    gemm_mainloop(Ap, Bp, 256, 256, kmax, As, Bs, acc);

    const int tid  = threadIdx.x;
    const int lane = tid & 63;
    const int wr   = (tid >> 7) & 1;
    const int wc   = (tid >> 6) & 1;
    const int r0 = (lane >> 4) << 2;
    const int c0 = lane & 15;
#pragma unroll
    for (int m = 0; m < 4; ++m) {
#pragma unroll
        for (int n = 0; n < 4; ++n) {
            const int d = ntl * 128 + wc * 64 + n * 16 + c0;
#pragma unroll
            for (int j = 0; j < 4; ++j) {
                const int t = mt * 128 + wr * 64 + m * 16 + r0 + j;
                O[((size_t)b * 256 + t) * 1024 + d] = acc[m][n][j];
            }
        }
    }
}

// ---------------- launcher ----------------
extern "C" void kernel_launch(void* const* d_in, const int* in_sizes, int n_in,
                              void* d_out, int out_size, void* d_ws, size_t ws_size,
                              hipStream_t stream) {
    (void)in_sizes; (void)n_in; (void)out_size; (void)ws_size;
    const float* x  = (const float*)d_in[0];
    const float* Wk = (const float*)d_in[1];
    const float* bk = (const float*)d_in[2];
    const float* Wq = (const float*)d_in[3];
    const float* bq = (const float*)d_in[4];
    const float* Wv = (const float*)d_in[5];
    const float* bv = (const float*)d_in[6];
    float* out = (float*)d_out;
    char* ws = (char*)d_ws;

    // ws layout (bytes):
    //   [0,            67108864)  xb   bf16 x  [32768][1024]
    //   [67108864,     73400320)  Wb   bf16 Wk|Wq|Wv  [3][1024][1024]
    //   [73400320,    140509184)  Kb   bf16 keys    [32768][1024]
    //   [140509184,   207618048)  Qb   bf16 queries [32768][1024]
    //   [207618048,   274726912)  Vt   bf16 values^T [128][1024][256]
    //   overlay after qkv: S f32 [128][256][256] at 0 ; P bf16 at 33554432
    u16*   xb = (u16*)(ws + 0);
    u16*   Wb = (u16*)(ws + 67108864);
    u16*   Kb = (u16*)(ws + 73400320);
    u16*   Qb = (u16*)(ws + 140509184);
    u16*   Vt = (u16*)(ws + 207618048);
    float* S  = (float*)(ws + 0);
    u16*   P  = (u16*)(ws + 33554432);

    cvt_f32_bf16<<<2048, 256, 0, stream>>>(x, xb, 33554432 / 4);
    cvt_f32_bf16<<<512, 256, 0, stream>>>(Wk, Wb, 1048576 / 4);
    cvt_f32_bf16<<<512, 256, 0, stream>>>(Wq, Wb + 1048576, 1048576 / 4);
    cvt_f32_bf16<<<512, 256, 0, stream>>>(Wv, Wb + 2097152, 1048576 / 4);
    qkv256<<<1536, 512, 131072, stream>>>(xb, Wb, bk, bq, bv, Kb, Qb, Vt);
    scores_gemm<<<384, 256, 0, stream>>>(Qb, Kb, S);
    softmax_p<<<8192, 256, 0, stream>>>(S, P);
    pv_gemm<<<2048, 256, 0, stream>>>(P, Vt, out);
}